// Round 5
// baseline (266.172 us; speedup 1.0000x reference)
//
#include <hip/hip_runtime.h>
#include <hip/hip_bf16.h>
#include <stdint.h>

// TFAttention: B=8,S=4096,N=512,K_DIM=512,HEADS=8,WS=128,HD=64
// R10: fuse x f32->bf16 cast INTO gemm1's A-staging (T14 issue-early/write-late):
//  - gemm256f<CASTA=true>: A loaded as f32 (8x float4/thread at tile top),
//    cvt+4x ds_write_b128 (swizzled addr) at tile end; B stays global_load_lds.
//    Eliminates 96 MB of cast traffic (64 read + 32 write); gemm1 pays +32 MB f32 fetch.
//  - cast kernel shrinks to weights-only (1 MB, 1024 blocks).
//  - K-loop schedule = R8-exact for the gld_lds parts (best measured: 63.5 us);
//    R9's tile-top burst reverted (regressed +4.5 us).
//  - attn keeps R9's LDS-bounce vectorized output store (measured neutral).
// 16x16x32 layouts: A/B: m=lane&15, k=(lane>>4)*8+j ; C/D: col=lane&15, row=(lane>>4)*4+reg
// LDS swizzle: 128B rows = 8 chunks of 16B; phys chunk p holds logical p^(row&7).

typedef __bf16 bf16;
typedef __bf16 bf16x8 __attribute__((ext_vector_type(8)));
typedef __bf16 bf16x4 __attribute__((ext_vector_type(4)));
typedef __bf16 bf16x2 __attribute__((ext_vector_type(2)));
typedef float  f32x4  __attribute__((ext_vector_type(4)));

#define DEV static __device__ __forceinline__

DEV void gld_lds16(const bf16* g, bf16* l) {
  __builtin_amdgcn_global_load_lds(
      (__attribute__((address_space(1))) void*)(g),
      (__attribute__((address_space(3))) void*)(l), 16, 0, 0);
}

// ---------------- weights-only cast kernel ----------------
__global__ void cast_w(const float* __restrict__ Wq, const float* __restrict__ Wk,
                       const float* __restrict__ Wv, const float* __restrict__ Wp,
                       bf16* __restrict__ wb) {
  int i = blockIdx.x * blockDim.x + threadIdx.x;  // 0..262143
  int e = i * 4;
  int off;
  const float* w;
  if (e < 786432) {
    int seg = e >> 18;
    off = e & 262143;
    w = (seg == 0) ? Wq : ((seg == 1) ? Wk : Wv);
  } else {
    off = e - 786432;
    w = Wp;
  }
  float4 v = *(const float4*)(w + off);
  bf16x4 o;
  o[0] = (bf16)v.x; o[1] = (bf16)v.y; o[2] = (bf16)v.z; o[3] = (bf16)v.w;
  *(bf16x4*)(wb + e) = o;
}

// ---------------- 256x256 fine-interleaved GEMM: C[M,NTILES*256] = A@B^T + bias ----
// 512 threads = 8 waves (2M x 4N), wave owns 128x64. BK=64, dbuf 128 KiB.
// CASTA: A is f32, reg-staged (issue loads tile-top, cvt+ds_write tile-end).
// else:  A is bf16 via global_load_lds, R8-exact 3/3/2 spread.
template <bool CASTA, bool BF16OUT, int NTILES>
__global__ __launch_bounds__(512, 2)
void gemm256f(const void* __restrict__ Aptr, const bf16* __restrict__ B,
              const float* __restrict__ bias0, const float* __restrict__ bias1,
              const float* __restrict__ bias2, void* __restrict__ Cout) {
  constexpr int Ntot = NTILES * 256;
  constexpr int NK = 8;  // K=512, BK=64
  __shared__ __align__(16) bf16 smem[2][2][256 * 64];  // [buf][A=0/B=1]

  const float* Af = (const float*)Aptr;
  const bf16*  Ab = (const bf16*)Aptr;

  const int tid = threadIdx.x;
  const int wave = tid >> 6, lane = tid & 63;
  const int wm = wave >> 2, wn = wave & 3;       // 2 x 4 wave grid
  const int lane15 = lane & 15, kq = lane >> 4;
  const int srow = lane >> 3;                    // staging row within group-of-8
  const int c8 = lane & 7;                       // logical 16B chunk
  const int sg = c8 ^ srow;                      // swizzled chunk (= phys pos)

  const int nb = gridDim.x;
  const int j = blockIdx.x;
  const int l = (j & 7) * (nb >> 3) + (j >> 3);  // XCD-chunk swizzle (nb % 8 == 0)
  const long row0 = (long)(l / NTILES) * 256;
  const long col0 = (long)(l % NTILES) * 256;

  f32x4 acc[8][4] = {};
  bf16x8 af0[4][2], af1[4][2], bq0[2][2], bq1[2][2];
  float4 areg[8];  // CASTA staging registers (DCE'd otherwise)

  // bf16 A (or B) group-of-8 staging via global_load_lds (pre-swizzled source)
#define STG_A(T, BUF, I)                                                       \
  gld_lds16(Ab + (row0 + wave * 32 + (I) * 8 + srow) * 512 + (long)(T) * 64 +  \
                sg * 8,                                                        \
            &smem[BUF][0][(wave * 32 + (I) * 8) * 64]);
#define STG_B(T, BUF, I)                                                       \
  gld_lds16(B + (col0 + wave * 32 + (I) * 8 + srow) * 512 + (long)(T) * 64 +   \
                sg * 8,                                                        \
            &smem[BUF][1][(wave * 32 + (I) * 8) * 64]);

  // f32 A staging: issue 8 float4 loads (natural chunk c8)
#define A_LOADF(T)                                                             \
  {                                                                            \
    const long kb_ = (long)(T) * 64;                                           \
    _Pragma("unroll") for (int i_ = 0; i_ < 4; ++i_) {                         \
      const float* p_ =                                                        \
          Af + (row0 + wave * 32 + i_ * 8 + srow) * 512 + kb_ + c8 * 8;        \
      areg[2 * i_]     = *(const float4*)(p_);                                 \
      areg[2 * i_ + 1] = *(const float4*)(p_ + 4);                             \
    }                                                                          \
  }
  // cvt + swizzled ds_write_b128 (phys chunk = c8 ^ row = sg)
#define A_WRITEF(BUF)                                                          \
  {                                                                            \
    _Pragma("unroll") for (int i_ = 0; i_ < 4; ++i_) {                         \
      bf16x8 o_;                                                               \
      o_[0] = (bf16)areg[2 * i_].x;     o_[1] = (bf16)areg[2 * i_].y;          \
      o_[2] = (bf16)areg[2 * i_].z;     o_[3] = (bf16)areg[2 * i_].w;          \
      o_[4] = (bf16)areg[2 * i_ + 1].x; o_[5] = (bf16)areg[2 * i_ + 1].y;      \
      o_[6] = (bf16)areg[2 * i_ + 1].z; o_[7] = (bf16)areg[2 * i_ + 1].w;      \
      *(bf16x8*)(&smem[BUF][0][(wave * 32 + i_ * 8 + srow) * 64 + sg * 8]) =   \
          o_;                                                                  \
    }                                                                          \
  }

#define READ_A(DST, QM, BUF)                                                   \
  {                                                                            \
    _Pragma("unroll") for (int mt_ = 0; mt_ < 4; ++mt_) {                      \
      const int r_ = wm * 128 + (QM) * 64 + mt_ * 16 + lane15;                 \
      const bf16* p_ = &smem[BUF][0][r_ * 64];                                 \
      _Pragma("unroll") for (int ks_ = 0; ks_ < 2; ++ks_) {                    \
        const int c_ = (ks_ * 4 + kq) ^ (r_ & 7);                              \
        DST[mt_][ks_] = *(const bf16x8*)(p_ + c_ * 8);                         \
      }                                                                        \
    }                                                                          \
  }

#define READ_B(DST, QN, BUF)                                                   \
  {                                                                            \
    _Pragma("unroll") for (int nt_ = 0; nt_ < 2; ++nt_) {                      \
      const int r_ = wn * 64 + (QN) * 32 + nt_ * 16 + lane15;                  \
      const bf16* p_ = &smem[BUF][1][r_ * 64];                                 \
      _Pragma("unroll") for (int ks_ = 0; ks_ < 2; ++ks_) {                    \
        const int c_ = (ks_ * 4 + kq) ^ (r_ & 7);                              \
        DST[nt_][ks_] = *(const bf16x8*)(p_ + c_ * 8);                         \
      }                                                                        \
    }                                                                          \
  }

  // ks OUTERMOST: 16 independent MFMAs between accumulator reuses
#define MMA_Q(AF, BF, QM, QN)                                                  \
  {                                                                            \
    __builtin_amdgcn_s_setprio(1);                                             \
    _Pragma("unroll") for (int ks_ = 0; ks_ < 2; ++ks_)                        \
    _Pragma("unroll") for (int mt_ = 0; mt_ < 4; ++mt_)                        \
    _Pragma("unroll") for (int nt_ = 0; nt_ < 2; ++nt_)                        \
      acc[(QM) * 4 + mt_][(QN) * 2 + nt_] =                                    \
          __builtin_amdgcn_mfma_f32_16x16x32_bf16(                             \
              AF[mt_][ks_], BF[nt_][ks_],                                      \
              acc[(QM) * 4 + mt_][(QN) * 2 + nt_], 0, 0, 0);                   \
    __builtin_amdgcn_s_setprio(0);                                             \
  }

  // prologue: tile 0 -> buf0, full drain once
  if constexpr (CASTA) {
    A_LOADF(0)
    STG_B(0, 0, 0) STG_B(0, 0, 1) STG_B(0, 0, 2) STG_B(0, 0, 3)
    A_WRITEF(0)
    asm volatile("s_waitcnt vmcnt(0) lgkmcnt(0)" ::: "memory");
  } else {
    STG_A(0, 0, 0) STG_A(0, 0, 1) STG_A(0, 0, 2) STG_A(0, 0, 3)
    STG_B(0, 0, 0) STG_B(0, 0, 1) STG_B(0, 0, 2) STG_B(0, 0, 3)
    asm volatile("s_waitcnt vmcnt(0)" ::: "memory");
  }
  __builtin_amdgcn_s_barrier();

  for (int kk = 0; kk < NK; ++kk) {
    const int cur = kk & 1, nxt = cur ^ 1;
    const bool st = (kk + 1 < NK);
    // ---- phase 0
    if (st) {
      if constexpr (CASTA) { A_LOADF(kk + 1) }  // issue-early: 3 phases of cover
    }
    READ_A(af0, 0, cur);
    READ_B(bq0, 0, cur);
    if (st) {
      if constexpr (CASTA) { STG_B(kk + 1, nxt, 0) STG_B(kk + 1, nxt, 1) }
      else { STG_A(kk + 1, nxt, 0) STG_A(kk + 1, nxt, 1) STG_B(kk + 1, nxt, 0) }
    }
    __builtin_amdgcn_s_barrier();
    MMA_Q(af0, bq0, 0, 0);
    __builtin_amdgcn_s_barrier();
    // ---- phase 1
    READ_B(bq1, 1, cur);
    if (st) {
      if constexpr (CASTA) { STG_B(kk + 1, nxt, 2) }
      else { STG_A(kk + 1, nxt, 2) STG_A(kk + 1, nxt, 3) STG_B(kk + 1, nxt, 1) }
    }
    __builtin_amdgcn_s_barrier();
    MMA_Q(af0, bq1, 0, 1);
    __builtin_amdgcn_s_barrier();
    // ---- phase 2
    READ_A(af1, 1, cur);
    if (st) {
      if constexpr (CASTA) { STG_B(kk + 1, nxt, 3) }
      else { STG_B(kk + 1, nxt, 2) STG_B(kk + 1, nxt, 3) }
    }
    __builtin_amdgcn_s_barrier();
    MMA_Q(af1, bq1, 1, 1);
    // ---- phase 3: no LDS reads -> merged MFMA cluster
    MMA_Q(af1, bq0, 1, 0);
    if (st) {
      if constexpr (CASTA) {
        A_WRITEF(nxt)  // write-late: compiler waits counted vmcnt for areg
        asm volatile("s_waitcnt vmcnt(0) lgkmcnt(0)" ::: "memory");
      } else {
        asm volatile("s_waitcnt vmcnt(0)" ::: "memory");
      }
      __builtin_amdgcn_s_barrier();
    }
  }

#undef STG_A
#undef STG_B
#undef A_LOADF
#undef A_WRITEF
#undef READ_A
#undef READ_B
#undef MMA_Q

  // epilogue: 16x16x32 C/D layout (col=lane&15, row=(lane>>4)*4+reg)
  const long crow = row0 + wm * 128;
  const long ccol = col0 + wn * 64;
  for (int m = 0; m < 8; ++m) {
    for (int n = 0; n < 4; ++n) {
      const long col = ccol + n * 16 + lane15;
      const float* bsel;
      if (NTILES == 6) {
        const int seg = (int)(col >> 9);
        bsel = (seg == 0) ? bias0 : ((seg == 1) ? bias1 : bias2);
      } else {
        bsel = bias0;
      }
      const float bias = bsel[col & 511];
      const long row = crow + m * 16 + kq * 4;
      for (int g = 0; g < 4; ++g) {
        const float v = acc[m][n][g] + bias;
        if (BF16OUT) ((bf16*)Cout)[(row + g) * Ntot + col] = (bf16)v;
        else         ((float*)Cout)[(row + g) * Ntot + col] = v;
      }
    }
  }
}

// ---------------- windowed attention (R4 core + vectorized output store) ----------------
__global__ __launch_bounds__(512, 4)
void attn_win(const bf16* __restrict__ QKV, bf16* __restrict__ Out) {
  __shared__ __align__(16) char smem[49152];
  bf16* Qs = (bf16*)smem;            // [128][64], chunk swizzle g^(row&7)
  bf16* Ks = Qs + 128 * 64;
  bf16* Ps = (bf16*)smem;            // [128][128], chunk swizzle g^(row&7)
  bf16* Vt = (bf16*)(smem + 32768);  // [64 d][128 t], chunk swizzle g^((d>>3)^(d&7))
  bf16* Os = (bf16*)smem;            // [128][64] output bounce (after PV)

  const int tid = threadIdx.x;
  const int wave = tid >> 6, lane = tid & 63;
  const int lane15 = lane & 15, quad = lane >> 4;
  const int win = blockIdx.x >> 3, head = blockIdx.x & 7;

  const bf16* Qg = QKV + (size_t)win * 128 * 1536 + head * 64;
  const bf16* Kg = Qg + 512;
  const bf16* Vg = Qg + 1024;

  {
    const int srow = lane >> 3;
    const int sg = (lane & 7) ^ srow;
    for (int i = 0; i < 2; ++i) {
      int r0 = (wave * 2 + i) * 8;
      gld_lds16(Qg + (size_t)(r0 + srow) * 1536 + sg * 8, Qs + r0 * 64 + lane * 8);
      gld_lds16(Kg + (size_t)(r0 + srow) * 1536 + sg * 8, Ks + r0 * 64 + lane * 8);
    }
  }
  {
    int tp = tid >> 3;
    int d0 = (tid & 7) * 8;
    bf16x8 v0 = *(const bf16x8*)(Vg + (size_t)(2 * tp) * 1536 + d0);
    bf16x8 v1 = *(const bf16x8*)(Vg + (size_t)(2 * tp + 1) * 1536 + d0);
    int gt = tp >> 2, po = tp & 3;
    for (int j = 0; j < 8; ++j) {
      int d = d0 + j;
      int p = gt ^ ((d >> 3) ^ (d & 7));
      bf16x2 pr;
      pr[0] = v0[j]; pr[1] = v1[j];
      *(bf16x2*)(Vt + d * 128 + p * 8 + po * 2) = pr;
    }
  }
  __syncthreads();

  f32x4 accs[8] = {};
  {
    bf16x8 aq[2];
    for (int s = 0; s < 2; ++s) {
      int row = wave * 16 + lane15;
      aq[s] = *(const bf16x8*)(Qs + row * 64 + (((s * 4 + quad) ^ (lane15 & 7)) * 8));
    }
    for (int c = 0; c < 8; ++c) {
      int row = c * 16 + lane15;
      for (int s = 0; s < 2; ++s) {
        bf16x8 bk = *(const bf16x8*)(Ks + row * 64 + (((s * 4 + quad) ^ (lane15 & 7)) * 8));
        accs[c] = __builtin_amdgcn_mfma_f32_16x16x32_bf16(aq[s], bk, accs[c], 0, 0, 0);
      }
    }
  }
  __syncthreads();

  const float scale = 0.125f;  // HD^-0.5
  for (int g = 0; g < 4; ++g) {
    float sum = 0.f;
    for (int c = 0; c < 8; ++c) {
      float e = __expf(accs[c][g] * scale);
      accs[c][g] = e;
      sum += e;
    }
    for (int mk = 1; mk <= 8; mk <<= 1) sum += __shfl_xor(sum, mk, 64);
    float inv = 1.0f / sum;
    int prow = wave * 16 + quad * 4 + g;
    int rsw = prow & 7;
    for (int c = 0; c < 8; ++c) {
      int col = c * 16 + lane15;
      int p = (col >> 3) ^ rsw;
      Ps[prow * 128 + p * 8 + (col & 7)] = (bf16)(accs[c][g] * inv);
    }
  }
  __syncthreads();

  f32x4 acco[4] = {};
  for (int kk = 0; kk < 4; ++kk) {
    int arow = wave * 16 + lane15;
    int pa = (kk * 4 + quad) ^ (arow & 7);
    bf16x8 a = *(const bf16x8*)(Ps + arow * 128 + pa * 8);
    for (int c = 0; c < 4; ++c) {
      int d = c * 16 + lane15;
      int p = (kk * 4 + quad) ^ ((d >> 3) ^ (d & 7));
      bf16x8 b = *(const bf16x8*)(Vt + d * 128 + p * 8);
      acco[c] = __builtin_amdgcn_mfma_f32_16x16x32_bf16(a, b, acco[c], 0, 0, 0);
    }
  }

  // ---- output: LDS bounce -> coalesced b128 stores ----
  __syncthreads();  // all PV reads of Ps/Vt done before overwrite
  {
    int rowb = wave * 16 + quad * 4;
    for (int c = 0; c < 4; ++c) {
      int col = c * 16 + lane15;
      for (int g = 0; g < 4; ++g)
        Os[(rowb + g) * 64 + col] = (bf16)acco[c][g];
    }
  }
  __syncthreads();
  {
    bf16* Og = Out + (size_t)win * 128 * 512 + head * 64;
    for (int i = 0; i < 2; ++i) {
      int idx = tid + i * 512;       // 0..1023 : 128 rows x 8 chunks of 16B
      int r = idx >> 3, ch = idx & 7;
      bf16x8 v = *(const bf16x8*)(Os + r * 64 + ch * 8);
      *(bf16x8*)(Og + (size_t)r * 512 + ch * 8) = v;
    }
  }
}

// ---------------- launch ----------------
extern "C" void kernel_launch(void* const* d_in, const int* in_sizes, int n_in,
                              void* d_out, int out_size, void* d_ws, size_t ws_size,
                              hipStream_t stream) {
  const float* x  = (const float*)d_in[0];
  const float* Wq = (const float*)d_in[1];
  const float* bq = (const float*)d_in[2];
  const float* Wk = (const float*)d_in[3];
  const float* bk = (const float*)d_in[4];
  const float* Wv = (const float*)d_in[5];
  const float* bv = (const float*)d_in[6];
  const float* Wp = (const float*)d_in[7];
  const float* bp = (const float*)d_in[8];

  bf16* Xb    = (bf16*)d_ws;            // (x no longer staged; offsets kept)
  bf16* Wqkvb = Xb + 16777216;
  bf16* Wpb   = Wqkvb + 786432;
  bf16* QKVb  = Wpb + 262144;
  bf16* AttnB = QKVb + 50331648;

  cast_w<<<1024, 256, 0, stream>>>(Wq, Wk, Wv, Wp, Wqkvb);
  gemm256f<true, true, 6><<<768, 512, 0, stream>>>(x, Wqkvb, bq, bk, bv, QKVb);
  attn_win<<<2048, 512, 0, stream>>>(QKVb, AttnB);
  gemm256f<false, false, 2><<<256, 512, 0, stream>>>(AttnB, Wpb, bp, bp, bp, d_out);
}

// Round 6
// 239.090 us; speedup vs baseline: 1.1133x; 1.1133x over previous
//
#include <hip/hip_runtime.h>
#include <hip/hip_bf16.h>
#include <stdint.h>

// TFAttention: B=8,S=4096,N=512,K_DIM=512,HEADS=8,WS=128,HD=64
// R11: R8-exact revert (best measured: 242.0 us, gemm1=63.5) PLUS one isolated,
//      correctness-neutral change: mid-phase s_barriers removed (7 -> 3 per
//      K-tile). All real hazards are covered by the tile-end vmcnt(0)+barrier;
//      per-wave ds_read->MFMA deps are compiler-enforced via lgkmcnt.
//      R10's cast-fusion reverted (reg-staging in the phase loop cost +52 us).
//      attn keeps R9's vectorized LDS-bounce output store (measured neutral).
// 16x16x32 layouts: A/B: m=lane&15, k=(lane>>4)*8+j ; C/D: col=lane&15, row=(lane>>4)*4+reg
// LDS swizzle: 128B rows = 8 chunks of 16B; phys chunk p holds logical p^(row&7).

typedef __bf16 bf16;
typedef __bf16 bf16x8 __attribute__((ext_vector_type(8)));
typedef __bf16 bf16x4 __attribute__((ext_vector_type(4)));
typedef __bf16 bf16x2 __attribute__((ext_vector_type(2)));
typedef float  f32x4  __attribute__((ext_vector_type(4)));

#define DEV static __device__ __forceinline__

DEV void gld_lds16(const bf16* g, bf16* l) {
  __builtin_amdgcn_global_load_lds(
      (__attribute__((address_space(1))) void*)(g),
      (__attribute__((address_space(3))) void*)(l), 16, 0, 0);
}

// ---------------- merged cast kernel ----------------
__global__ void cast_all(const float* __restrict__ x,
                         const float* __restrict__ Wq, const float* __restrict__ Wk,
                         const float* __restrict__ Wv, const float* __restrict__ Wp,
                         bf16* __restrict__ xb, bf16* __restrict__ wb) {
  int i = blockIdx.x * blockDim.x + threadIdx.x;
  const float* src;
  bf16* dst;
  if (i < 4194304) {
    src = x + i * 4;
    dst = xb + i * 4;
  } else {
    int e = (i - 4194304) * 4;
    int off;
    const float* w;
    if (e < 786432) {
      int seg = e >> 18;
      off = e & 262143;
      w = (seg == 0) ? Wq : ((seg == 1) ? Wk : Wv);
    } else {
      off = e - 786432;
      w = Wp;
    }
    src = w + off;
    dst = wb + e;
  }
  float4 v = *(const float4*)src;
  bf16x4 o;
  o[0] = (bf16)v.x; o[1] = (bf16)v.y; o[2] = (bf16)v.z; o[3] = (bf16)v.w;
  *(bf16x4*)dst = o;
}

// ---------------- 256x256 fine-interleaved GEMM: C[M,NTILES*256] = A@B^T + bias ----
// 512 threads = 8 waves (2M x 4N), wave owns 128x64. BK=64, dbuf 128 KiB.
// Per K-tile: 3 phases (R8's read/stage spread), ONE barrier per phase.
template <bool BF16OUT, int NTILES>
__global__ __launch_bounds__(512, 2)
void gemm256f(const bf16* __restrict__ A, const bf16* __restrict__ B,
              const float* __restrict__ bias0, const float* __restrict__ bias1,
              const float* __restrict__ bias2, void* __restrict__ Cout) {
  constexpr int Ntot = NTILES * 256;
  constexpr int NK = 8;  // K=512, BK=64
  __shared__ __align__(16) bf16 smem[2][2][256 * 64];  // [buf][A=0/B=1]

  const int tid = threadIdx.x;
  const int wave = tid >> 6, lane = tid & 63;
  const int wm = wave >> 2, wn = wave & 3;       // 2 x 4 wave grid
  const int lane15 = lane & 15, kq = lane >> 4;
  const int srow = lane >> 3, sg = (lane & 7) ^ srow;  // staging pre-swizzle

  const int nb = gridDim.x;
  const int j = blockIdx.x;
  const int l = (j & 7) * (nb >> 3) + (j >> 3);  // XCD-chunk swizzle (nb % 8 == 0)
  const long row0 = (long)(l / NTILES) * 256;
  const long col0 = (long)(l % NTILES) * 256;

  f32x4 acc[8][4] = {};
  bf16x8 af0[4][2], af1[4][2], bq0[2][2], bq1[2][2];

  // one A (or B) row-group-of-8 staging load for K-tile T into buffer BUF
#define STG_A(T, BUF, I)                                                       \
  gld_lds16(A + (row0 + wave * 32 + (I) * 8 + srow) * 512 + (long)(T) * 64 +   \
                sg * 8,                                                        \
            &smem[BUF][0][(wave * 32 + (I) * 8) * 64]);
#define STG_B(T, BUF, I)                                                       \
  gld_lds16(B + (col0 + wave * 32 + (I) * 8 + srow) * 512 + (long)(T) * 64 +   \
                sg * 8,                                                        \
            &smem[BUF][1][(wave * 32 + (I) * 8) * 64]);

#define READ_A(DST, QM, BUF)                                                   \
  {                                                                            \
    _Pragma("unroll") for (int mt_ = 0; mt_ < 4; ++mt_) {                      \
      const int r_ = wm * 128 + (QM) * 64 + mt_ * 16 + lane15;                 \
      const bf16* p_ = &smem[BUF][0][r_ * 64];                                 \
      _Pragma("unroll") for (int ks_ = 0; ks_ < 2; ++ks_) {                    \
        const int c_ = (ks_ * 4 + kq) ^ (r_ & 7);                              \
        DST[mt_][ks_] = *(const bf16x8*)(p_ + c_ * 8);                         \
      }                                                                        \
    }                                                                          \
  }

#define READ_B(DST, QN, BUF)                                                   \
  {                                                                            \
    _Pragma("unroll") for (int nt_ = 0; nt_ < 2; ++nt_) {                      \
      const int r_ = wn * 64 + (QN) * 32 + nt_ * 16 + lane15;                  \
      const bf16* p_ = &smem[BUF][1][r_ * 64];                                 \
      _Pragma("unroll") for (int ks_ = 0; ks_ < 2; ++ks_) {                    \
        const int c_ = (ks_ * 4 + kq) ^ (r_ & 7);                              \
        DST[nt_][ks_] = *(const bf16x8*)(p_ + c_ * 8);                         \
      }                                                                        \
    }                                                                          \
  }

  // ks OUTERMOST: 16 independent MFMAs between accumulator reuses
#define MMA_Q(AF, BF, QM, QN)                                                  \
  {                                                                            \
    __builtin_amdgcn_s_setprio(1);                                             \
    _Pragma("unroll") for (int ks_ = 0; ks_ < 2; ++ks_)                        \
    _Pragma("unroll") for (int mt_ = 0; mt_ < 4; ++mt_)                        \
    _Pragma("unroll") for (int nt_ = 0; nt_ < 2; ++nt_)                        \
      acc[(QM) * 4 + mt_][(QN) * 2 + nt_] =                                    \
          __builtin_amdgcn_mfma_f32_16x16x32_bf16(                             \
              AF[mt_][ks_], BF[nt_][ks_],                                      \
              acc[(QM) * 4 + mt_][(QN) * 2 + nt_], 0, 0, 0);                   \
    __builtin_amdgcn_s_setprio(0);                                             \
  }

  // prologue: tile 0 -> buf0, full drain once
  {
    STG_A(0, 0, 0) STG_A(0, 0, 1) STG_A(0, 0, 2) STG_A(0, 0, 3)
    STG_B(0, 0, 0) STG_B(0, 0, 1) STG_B(0, 0, 2) STG_B(0, 0, 3)
  }
  asm volatile("s_waitcnt vmcnt(0)" ::: "memory");
  __builtin_amdgcn_s_barrier();

  for (int kk = 0; kk < NK; ++kk) {
    const int cur = kk & 1, nxt = cur ^ 1;
    const bool st = (kk + 1 < NK);
    // ---- phase 0: reads + 3 staging loads + MMA(0,0) + barrier
    READ_A(af0, 0, cur);
    READ_B(bq0, 0, cur);
    if (st) { STG_A(kk + 1, nxt, 0) STG_A(kk + 1, nxt, 1) STG_B(kk + 1, nxt, 0) }
    MMA_Q(af0, bq0, 0, 0);
    __builtin_amdgcn_s_barrier();
    // ---- phase 1: reads + 3 staging loads + MMA(0,1) + barrier
    READ_B(bq1, 1, cur);
    if (st) { STG_A(kk + 1, nxt, 2) STG_A(kk + 1, nxt, 3) STG_B(kk + 1, nxt, 1) }
    MMA_Q(af0, bq1, 0, 1);
    __builtin_amdgcn_s_barrier();
    // ---- phase 2: reads + 2 staging loads + MMA(1,1)+MMA(1,0), tile-end sync
    READ_A(af1, 1, cur);
    if (st) { STG_B(kk + 1, nxt, 2) STG_B(kk + 1, nxt, 3) }
    MMA_Q(af1, bq1, 1, 1);
    MMA_Q(af1, bq0, 1, 0);
    if (st) {
      asm volatile("s_waitcnt vmcnt(0)" ::: "memory");  // kk+1 landed
      __builtin_amdgcn_s_barrier();                     // buf swap safe
    }
  }

#undef STG_A
#undef STG_B
#undef READ_A
#undef READ_B
#undef MMA_Q

  // epilogue: 16x16x32 C/D layout (col=lane&15, row=(lane>>4)*4+reg)
  const long crow = row0 + wm * 128;
  const long ccol = col0 + wn * 64;
  for (int m = 0; m < 8; ++m) {
    for (int n = 0; n < 4; ++n) {
      const long col = ccol + n * 16 + lane15;
      const float* bsel;
      if (NTILES == 6) {
        const int seg = (int)(col >> 9);
        bsel = (seg == 0) ? bias0 : ((seg == 1) ? bias1 : bias2);
      } else {
        bsel = bias0;
      }
      const float bias = bsel[col & 511];
      const long row = crow + m * 16 + kq * 4;
      for (int g = 0; g < 4; ++g) {
        const float v = acc[m][n][g] + bias;
        if (BF16OUT) ((bf16*)Cout)[(row + g) * Ntot + col] = (bf16)v;
        else         ((float*)Cout)[(row + g) * Ntot + col] = v;
      }
    }
  }
}

// ---------------- windowed attention (R4 core + vectorized output store) ----------------
__global__ __launch_bounds__(512, 4)
void attn_win(const bf16* __restrict__ QKV, bf16* __restrict__ Out) {
  __shared__ __align__(16) char smem[49152];
  bf16* Qs = (bf16*)smem;            // [128][64], chunk swizzle g^(row&7)
  bf16* Ks = Qs + 128 * 64;
  bf16* Ps = (bf16*)smem;            // [128][128], chunk swizzle g^(row&7)
  bf16* Vt = (bf16*)(smem + 32768);  // [64 d][128 t], chunk swizzle g^((d>>3)^(d&7))
  bf16* Os = (bf16*)smem;            // [128][64] output bounce (after PV)

  const int tid = threadIdx.x;
  const int wave = tid >> 6, lane = tid & 63;
  const int lane15 = lane & 15, quad = lane >> 4;
  const int win = blockIdx.x >> 3, head = blockIdx.x & 7;

  const bf16* Qg = QKV + (size_t)win * 128 * 1536 + head * 64;
  const bf16* Kg = Qg + 512;
  const bf16* Vg = Qg + 1024;

  {
    const int srow = lane >> 3;
    const int sg = (lane & 7) ^ srow;
    for (int i = 0; i < 2; ++i) {
      int r0 = (wave * 2 + i) * 8;
      gld_lds16(Qg + (size_t)(r0 + srow) * 1536 + sg * 8, Qs + r0 * 64 + lane * 8);
      gld_lds16(Kg + (size_t)(r0 + srow) * 1536 + sg * 8, Ks + r0 * 64 + lane * 8);
    }
  }
  {
    int tp = tid >> 3;
    int d0 = (tid & 7) * 8;
    bf16x8 v0 = *(const bf16x8*)(Vg + (size_t)(2 * tp) * 1536 + d0);
    bf16x8 v1 = *(const bf16x8*)(Vg + (size_t)(2 * tp + 1) * 1536 + d0);
    int gt = tp >> 2, po = tp & 3;
    for (int j = 0; j < 8; ++j) {
      int d = d0 + j;
      int p = gt ^ ((d >> 3) ^ (d & 7));
      bf16x2 pr;
      pr[0] = v0[j]; pr[1] = v1[j];
      *(bf16x2*)(Vt + d * 128 + p * 8 + po * 2) = pr;
    }
  }
  __syncthreads();

  f32x4 accs[8] = {};
  {
    bf16x8 aq[2];
    for (int s = 0; s < 2; ++s) {
      int row = wave * 16 + lane15;
      aq[s] = *(const bf16x8*)(Qs + row * 64 + (((s * 4 + quad) ^ (lane15 & 7)) * 8));
    }
    for (int c = 0; c < 8; ++c) {
      int row = c * 16 + lane15;
      for (int s = 0; s < 2; ++s) {
        bf16x8 bk = *(const bf16x8*)(Ks + row * 64 + (((s * 4 + quad) ^ (lane15 & 7)) * 8));
        accs[c] = __builtin_amdgcn_mfma_f32_16x16x32_bf16(aq[s], bk, accs[c], 0, 0, 0);
      }
    }
  }
  __syncthreads();

  const float scale = 0.125f;  // HD^-0.5
  for (int g = 0; g < 4; ++g) {
    float sum = 0.f;
    for (int c = 0; c < 8; ++c) {
      float e = __expf(accs[c][g] * scale);
      accs[c][g] = e;
      sum += e;
    }
    for (int mk = 1; mk <= 8; mk <<= 1) sum += __shfl_xor(sum, mk, 64);
    float inv = 1.0f / sum;
    int prow = wave * 16 + quad * 4 + g;
    int rsw = prow & 7;
    for (int c = 0; c < 8; ++c) {
      int col = c * 16 + lane15;
      int p = (col >> 3) ^ rsw;
      Ps[prow * 128 + p * 8 + (col & 7)] = (bf16)(accs[c][g] * inv);
    }
  }
  __syncthreads();

  f32x4 acco[4] = {};
  for (int kk = 0; kk < 4; ++kk) {
    int arow = wave * 16 + lane15;
    int pa = (kk * 4 + quad) ^ (arow & 7);
    bf16x8 a = *(const bf16x8*)(Ps + arow * 128 + pa * 8);
    for (int c = 0; c < 4; ++c) {
      int d = c * 16 + lane15;
      int p = (kk * 4 + quad) ^ ((d >> 3) ^ (d & 7));
      bf16x8 b = *(const bf16x8*)(Vt + d * 128 + p * 8);
      acco[c] = __builtin_amdgcn_mfma_f32_16x16x32_bf16(a, b, acco[c], 0, 0, 0);
    }
  }

  // ---- output: LDS bounce -> coalesced b128 stores ----
  __syncthreads();  // all PV reads of Ps/Vt done before overwrite
  {
    int rowb = wave * 16 + quad * 4;
    for (int c = 0; c < 4; ++c) {
      int col = c * 16 + lane15;
      for (int g = 0; g < 4; ++g)
        Os[(rowb + g) * 64 + col] = (bf16)acco[c][g];
    }
  }
  __syncthreads();
  {
    bf16* Og = Out + (size_t)win * 128 * 512 + head * 64;
    for (int i = 0; i < 2; ++i) {
      int idx = tid + i * 512;       // 0..1023 : 128 rows x 8 chunks of 16B
      int r = idx >> 3, ch = idx & 7;
      bf16x8 v = *(const bf16x8*)(Os + r * 64 + ch * 8);
      *(bf16x8*)(Og + (size_t)r * 512 + ch * 8) = v;
    }
  }
}

// ---------------- launch ----------------
extern "C" void kernel_launch(void* const* d_in, const int* in_sizes, int n_in,
                              void* d_out, int out_size, void* d_ws, size_t ws_size,
                              hipStream_t stream) {
  const float* x  = (const float*)d_in[0];
  const float* Wq = (const float*)d_in[1];
  const float* bq = (const float*)d_in[2];
  const float* Wk = (const float*)d_in[3];
  const float* bk = (const float*)d_in[4];
  const float* Wv = (const float*)d_in[5];
  const float* bv = (const float*)d_in[6];
  const float* Wp = (const float*)d_in[7];
  const float* bp = (const float*)d_in[8];

  bf16* Xb    = (bf16*)d_ws;
  bf16* Wqkvb = Xb + 16777216;
  bf16* Wpb   = Wqkvb + 786432;
  bf16* QKVb  = Wpb + 262144;
  bf16* AttnB = QKVb + 50331648;

  cast_all<<<17408, 256, 0, stream>>>(x, Wq, Wk, Wv, Wp, Xb, Wqkvb);
  gemm256f<true, 6><<<768, 512, 0, stream>>>(Xb, Wqkvb, bq, bk, bv, QKVb);
  attn_win<<<2048, 512, 0, stream>>>(QKVb, AttnB);
  gemm256f<false, 2><<<256, 512, 0, stream>>>(AttnB, Wpb, bp, bp, bp, d_out);
}